// Round 1
// 200.161 us; speedup vs baseline: 2.2760x; 2.2760x over previous
//
#include <hip/hip_runtime.h>
#include <hip/hip_bf16.h>
#include <math.h>

#define B_ 4
#define DIM_ 256
#define H_ 128
#define W_ 128
#define HW_ (H_ * W_)
#define AD_ 64
#define HEADS_ 4
#define HD_ 16
#define WS_ 5
#define PAD_ 2

// ---------------- weight transpose: (O,C) row-major -> (C,O) c-major ----------
// Makes every weight access in the GEMM kernels thread-invariant -> s_load.
__global__ __launch_bounds__(256) void k_transpose_w(
    const float* __restrict__ Wq, const float* __restrict__ Wk,
    const float* __restrict__ Wv, const float* __restrict__ Wo,
    float* __restrict__ WqT, float* __restrict__ WkT,
    float* __restrict__ WvT, float* __restrict__ WoT)
{
    int i = blockIdx.x * blockDim.x + threadIdx.x;
    if (i >= AD_ * DIM_) return;
    // Wq/Wk/Wv: (64,256) -> (256,64)
    int o = i / DIM_, c = i % DIM_;
    WqT[c * AD_ + o] = Wq[i];
    WkT[c * AD_ + o] = Wk[i];
    WvT[c * AD_ + o] = Wv[i];
    // Wo: (256,64) -> (64,256)
    int o2 = i / AD_, c2 = i % AD_;
    WoT[c2 * DIM_ + o2] = Wo[i];
}

// ---------------- fused QKV projection ---------------------------------------
// Block = 768 threads = 12 waves over the SAME 64 pixels.
//   waves 0..3  : Q head w   (read q_in,  l2-normalize)
//   waves 4..7  : K head w-4 (read kv_in, l2-normalize)
//   waves 8..11 : V head w-8 (read kv_in, no norm)
// lane = pixel. 16 outputs/thread -> low VGPR, 24 waves/CU occupancy.
// Weight row pointer is wave-uniform -> s_load. FMA order over c is identical
// to the previous kernel -> bitwise-identical outputs.
__global__ __launch_bounds__(768) void k_qkv(
    const float* __restrict__ q_in, const float* __restrict__ kv_in,
    const float* __restrict__ WqT, const float* __restrict__ WkT,
    const float* __restrict__ WvT,
    float* __restrict__ qh, float* __restrict__ kh, float* __restrict__ vv)
{
    int lane = threadIdx.x & 63;
    int w    = __builtin_amdgcn_readfirstlane((int)(threadIdx.x >> 6)); // 0..11
    int head = w & 3;
    int pix  = blockIdx.x * 64 + lane;        // 0 .. 65535
    int b = pix >> 14;
    int p = pix & (HW_ - 1);

    const float* src = (w < 4) ? q_in : kv_in;
    const float* WT  = (w < 4) ? WqT : (w < 8) ? WkT : WvT;
    float* dstb      = (w < 4) ? qh  : (w < 8) ? kh  : vv;

    const float* xp = src + (size_t)b * DIM_ * HW_ + p;
    const float* wp = WT + head * HD_;        // wave-uniform

    float acc[HD_];
#pragma unroll
    for (int d = 0; d < HD_; ++d) acc[d] = 0.f;

#pragma unroll 4
    for (int c = 0; c < DIM_; ++c) {
        float xv = xp[(size_t)c * HW_];       // coalesced across lanes
        const float* wr = wp + c * AD_;       // thread-invariant -> s_load
#pragma unroll
        for (int d = 0; d < HD_; ++d) acc[d] = fmaf(wr[d], xv, acc[d]);
    }

    if (w < 8) {                              // wave-uniform branch
        float s = 0.f;
#pragma unroll
        for (int d = 0; d < HD_; ++d) s = fmaf(acc[d], acc[d], s);
        float inv = 1.f / fmaxf(sqrtf(s), 1e-12f);
#pragma unroll
        for (int d = 0; d < HD_; ++d) acc[d] *= inv;
    }

    float* dst = dstb + (((size_t)b * HEADS_ + head) * HW_ + p) * HD_;
    *(float4*)(dst + 0)  = make_float4(acc[0],  acc[1],  acc[2],  acc[3]);
    *(float4*)(dst + 4)  = make_float4(acc[4],  acc[5],  acc[6],  acc[7]);
    *(float4*)(dst + 8)  = make_float4(acc[8],  acc[9],  acc[10], acc[11]);
    *(float4*)(dst + 12) = make_float4(acc[12], acc[13], acc[14], acc[15]);
}

__device__ __forceinline__ int refl(int i, int n) {
    if (i < 0) i = -i;
    if (i >= n) i = 2 * n - 2 - i;
    return i;
}

// ---------------- sliding-window attention: one thread per (b,head,pixel) ----
// q,k already l2-normalized. ao layout: [b][p][h*16+d] (pixel-major for oproj).
__global__ __launch_bounds__(256) void k_attn(
    const float* __restrict__ qh, const float* __restrict__ kh,
    const float* __restrict__ vv, float* __restrict__ ao)
{
    int gid = blockIdx.x * blockDim.x + threadIdx.x;   // (b*4+h)*HW + p
    int p  = gid & (HW_ - 1);
    int bh = gid >> 14;
    int y = p >> 7, x = p & (W_ - 1);

    const float* qp = qh + ((size_t)bh * HW_ + p) * HD_;
    float4 q0 = *(const float4*)(qp + 0);
    float4 q1 = *(const float4*)(qp + 4);
    float4 q2 = *(const float4*)(qp + 8);
    float4 q3 = *(const float4*)(qp + 12);

    float logit[WS_ * WS_];
    int   nidx [WS_ * WS_];
#pragma unroll
    for (int i = 0; i < WS_; ++i) {
        int ry = refl(y + i - PAD_, H_);
#pragma unroll
        for (int j = 0; j < WS_; ++j) {
            int rx = refl(x + j - PAD_, W_);
            int np_ = ry * W_ + rx;
            nidx[i*WS_ + j] = np_;
            const float* kp = kh + ((size_t)bh * HW_ + np_) * HD_;
            float4 ka = *(const float4*)(kp + 0);
            float4 kb = *(const float4*)(kp + 4);
            float4 kc = *(const float4*)(kp + 8);
            float4 kd = *(const float4*)(kp + 12);
            float d = 0.f;
            d = fmaf(q0.x, ka.x, d); d = fmaf(q0.y, ka.y, d);
            d = fmaf(q0.z, ka.z, d); d = fmaf(q0.w, ka.w, d);
            d = fmaf(q1.x, kb.x, d); d = fmaf(q1.y, kb.y, d);
            d = fmaf(q1.z, kb.z, d); d = fmaf(q1.w, kb.w, d);
            d = fmaf(q2.x, kc.x, d); d = fmaf(q2.y, kc.y, d);
            d = fmaf(q2.z, kc.z, d); d = fmaf(q2.w, kc.w, d);
            d = fmaf(q3.x, kd.x, d); d = fmaf(q3.y, kd.y, d);
            d = fmaf(q3.z, kd.z, d); d = fmaf(q3.w, kd.w, d);
            logit[i*WS_ + j] = d;
        }
    }

    float m = logit[0];
#pragma unroll
    for (int w = 1; w < WS_*WS_; ++w) m = fmaxf(m, logit[w]);
    float s = 0.f;
#pragma unroll
    for (int w = 0; w < WS_*WS_; ++w) { float e = expf(logit[w] - m); logit[w] = e; s += e; }
    float invs = 1.f / s;

    float a[HD_];
#pragma unroll
    for (int d = 0; d < HD_; ++d) a[d] = 0.f;
#pragma unroll
    for (int w = 0; w < WS_*WS_; ++w) {
        float wt = logit[w] * invs;
        const float* vp = vv + ((size_t)bh * HW_ + nidx[w]) * HD_;
        float4 va = *(const float4*)(vp + 0);
        float4 vb = *(const float4*)(vp + 4);
        float4 vc = *(const float4*)(vp + 8);
        float4 vd = *(const float4*)(vp + 12);
        a[0]  = fmaf(wt, va.x, a[0]);  a[1]  = fmaf(wt, va.y, a[1]);
        a[2]  = fmaf(wt, va.z, a[2]);  a[3]  = fmaf(wt, va.w, a[3]);
        a[4]  = fmaf(wt, vb.x, a[4]);  a[5]  = fmaf(wt, vb.y, a[5]);
        a[6]  = fmaf(wt, vb.z, a[6]);  a[7]  = fmaf(wt, vb.w, a[7]);
        a[8]  = fmaf(wt, vc.x, a[8]);  a[9]  = fmaf(wt, vc.y, a[9]);
        a[10] = fmaf(wt, vc.z, a[10]); a[11] = fmaf(wt, vc.w, a[11]);
        a[12] = fmaf(wt, vd.x, a[12]); a[13] = fmaf(wt, vd.y, a[13]);
        a[14] = fmaf(wt, vd.z, a[14]); a[15] = fmaf(wt, vd.w, a[15]);
    }

    int b = bh >> 2, h = bh & 3;
    float* aop = ao + ((size_t)b * HW_ + p) * AD_ + h * HD_;
    *(float4*)(aop + 0)  = make_float4(a[0],  a[1],  a[2],  a[3]);
    *(float4*)(aop + 4)  = make_float4(a[4],  a[5],  a[6],  a[7]);
    *(float4*)(aop + 8)  = make_float4(a[8],  a[9],  a[10], a[11]);
    *(float4*)(aop + 12) = make_float4(a[12], a[13], a[14], a[15]);
}

// ---------------- output projection: out[b, oc, p] = sum_c WoT[c][oc] * ao[b,p,c]
// Block = 4 waves over the same 64 pixels; each wave owns a 64-wide o-chunk.
__global__ __launch_bounds__(256) void k_oproj(
    const float* __restrict__ ao, const float* __restrict__ WoT,
    float* __restrict__ out)
{
    int lane = threadIdx.x & 63;
    int och  = __builtin_amdgcn_readfirstlane((int)(threadIdx.x >> 6)); // 0..3, SGPR
    int pix  = blockIdx.x * 64 + lane;                                  // 0..65535
    int b = pix >> 14;
    int p = pix & (HW_ - 1);
    const float* xp = ao + (size_t)pix * AD_;

    float acc[64];
#pragma unroll
    for (int o = 0; o < 64; ++o) acc[o] = 0.f;

    for (int c4 = 0; c4 < AD_ / 4; ++c4) {
        float4 xv = *(const float4*)(xp + c4 * 4);
#pragma unroll
        for (int cc = 0; cc < 4; ++cc) {
            float xs = (cc == 0) ? xv.x : (cc == 1) ? xv.y : (cc == 2) ? xv.z : xv.w;
            const float* wr = WoT + (size_t)(c4*4 + cc) * DIM_ + och * 64;  // uniform -> s_load
#pragma unroll
            for (int o = 0; o < 64; ++o) acc[o] = fmaf(wr[o], xs, acc[o]);
        }
    }

    float* op = out + (size_t)b * DIM_ * HW_ + (size_t)och * 64 * HW_ + p;
#pragma unroll
    for (int o = 0; o < 64; ++o) op[(size_t)o * HW_] = acc[o];
}

extern "C" void kernel_launch(void* const* d_in, const int* in_sizes, int n_in,
                              void* d_out, int out_size, void* d_ws, size_t ws_size,
                              hipStream_t stream) {
    const float* q_in  = (const float*)d_in[0];
    const float* kv_in = (const float*)d_in[1];
    const float* Wq    = (const float*)d_in[2];
    const float* Wk    = (const float*)d_in[3];
    const float* Wv    = (const float*)d_in[4];
    const float* Wo    = (const float*)d_in[5];
    float* out = (float*)d_out;

    float* wsf = (float*)d_ws;
    float* WqT = wsf;
    float* WkT = WqT + AD_ * DIM_;
    float* WvT = WkT + AD_ * DIM_;
    float* WoT = WvT + AD_ * DIM_;
    size_t tens = (size_t)B_ * HEADS_ * HW_ * HD_;   // 4,194,304 floats
    float* qh = WoT + AD_ * DIM_;
    float* kh = qh + tens;
    float* vv = kh + tens;
    float* ao = vv + tens;

    k_transpose_w<<<dim3(64), dim3(256), 0, stream>>>(Wq, Wk, Wv, Wo, WqT, WkT, WvT, WoT);
    k_qkv<<<dim3(HW_ * B_ / 64), dim3(768), 0, stream>>>(q_in, kv_in, WqT, WkT, WvT, qh, kh, vv);
    k_attn <<<dim3(1024), dim3(256), 0, stream>>>(qh, kh, vv, ao);
    k_oproj<<<dim3(1024), dim3(256), 0, stream>>>(ao, WoT, out);
}

// Round 2
// 195.183 us; speedup vs baseline: 2.3341x; 1.0255x over previous
//
#include <hip/hip_runtime.h>
#include <hip/hip_bf16.h>
#include <math.h>

#define B_ 4
#define DIM_ 256
#define H_ 128
#define W_ 128
#define HW_ (H_ * W_)
#define AD_ 64
#define HEADS_ 4
#define HD_ 16
#define WS_ 5
#define PAD_ 2

// ---------------- weight transpose: (O,C) row-major -> (C,O) c-major ----------
// Makes every weight access in the GEMM kernels thread-invariant -> s_load.
__global__ __launch_bounds__(256) void k_transpose_w(
    const float* __restrict__ Wq, const float* __restrict__ Wk,
    const float* __restrict__ Wv, const float* __restrict__ Wo,
    float* __restrict__ WqT, float* __restrict__ WkT,
    float* __restrict__ WvT, float* __restrict__ WoT)
{
    int i = blockIdx.x * blockDim.x + threadIdx.x;
    if (i >= AD_ * DIM_) return;
    // Wq/Wk/Wv: (64,256) -> (256,64)
    int o = i / DIM_, c = i % DIM_;
    WqT[c * AD_ + o] = Wq[i];
    WkT[c * AD_ + o] = Wk[i];
    WvT[c * AD_ + o] = Wv[i];
    // Wo: (256,64) -> (64,256)
    int o2 = i / AD_, c2 = i % AD_;
    WoT[c2 * DIM_ + o2] = Wo[i];
}

// ---------------- fused QKV projection, 2 pixels/thread -----------------------
// Block = 768 threads = 12 waves over the SAME 128 consecutive pixels.
//   waves 0..3  : Q head w   (read q_in,  l2-normalize)
//   waves 4..7  : K head w-4 (read kv_in, l2-normalize)
//   waves 8..11 : V head w-8 (read kv_in, no norm)
// Each lane owns 2 adjacent pixels -> one float2 load feeds 32 FMAs
// (2x the latency cover of the 1-pixel version at the same occupancy).
// Weight row pointer is wave-uniform -> s_load. FMA order over c per output
// is identical to before -> identical results.
__global__ __launch_bounds__(768) void k_qkv(
    const float* __restrict__ q_in, const float* __restrict__ kv_in,
    const float* __restrict__ WqT, const float* __restrict__ WkT,
    const float* __restrict__ WvT,
    float* __restrict__ qh, float* __restrict__ kh, float* __restrict__ vv)
{
    int lane = threadIdx.x & 63;
    int w    = __builtin_amdgcn_readfirstlane((int)(threadIdx.x >> 6)); // 0..11
    int head = w & 3;
    int pix  = blockIdx.x * 128 + lane * 2;   // 2 consecutive pixels
    int b = pix >> 14;                        // uniform per block (128 | 16384)
    int p = pix & (HW_ - 1);

    const float* src = (w < 4) ? q_in : kv_in;
    const float* WT  = (w < 4) ? WqT : (w < 8) ? WkT : WvT;
    float* dstb      = (w < 4) ? qh  : (w < 8) ? kh  : vv;

    const float* xp = src + (size_t)b * DIM_ * HW_ + p;
    const float* wp = WT + head * HD_;        // wave-uniform

    float acc0[HD_], acc1[HD_];
#pragma unroll
    for (int d = 0; d < HD_; ++d) { acc0[d] = 0.f; acc1[d] = 0.f; }

#pragma unroll 4
    for (int c = 0; c < DIM_; ++c) {
        float2 xv = *(const float2*)(xp + (size_t)c * HW_);  // coalesced 8B/lane
        const float* wr = wp + c * AD_;       // thread-invariant -> s_load
#pragma unroll
        for (int d = 0; d < HD_; ++d) {
            acc0[d] = fmaf(wr[d], xv.x, acc0[d]);
            acc1[d] = fmaf(wr[d], xv.y, acc1[d]);
        }
    }

    if (w < 8) {                              // wave-uniform branch
        float s0 = 0.f, s1 = 0.f;
#pragma unroll
        for (int d = 0; d < HD_; ++d) {
            s0 = fmaf(acc0[d], acc0[d], s0);
            s1 = fmaf(acc1[d], acc1[d], s1);
        }
        float inv0 = 1.f / fmaxf(sqrtf(s0), 1e-12f);
        float inv1 = 1.f / fmaxf(sqrtf(s1), 1e-12f);
#pragma unroll
        for (int d = 0; d < HD_; ++d) { acc0[d] *= inv0; acc1[d] *= inv1; }
    }

    float* dst = dstb + (((size_t)b * HEADS_ + head) * HW_ + p) * HD_;
    *(float4*)(dst + 0)  = make_float4(acc0[0],  acc0[1],  acc0[2],  acc0[3]);
    *(float4*)(dst + 4)  = make_float4(acc0[4],  acc0[5],  acc0[6],  acc0[7]);
    *(float4*)(dst + 8)  = make_float4(acc0[8],  acc0[9],  acc0[10], acc0[11]);
    *(float4*)(dst + 12) = make_float4(acc0[12], acc0[13], acc0[14], acc0[15]);
    *(float4*)(dst + 16) = make_float4(acc1[0],  acc1[1],  acc1[2],  acc1[3]);
    *(float4*)(dst + 20) = make_float4(acc1[4],  acc1[5],  acc1[6],  acc1[7]);
    *(float4*)(dst + 24) = make_float4(acc1[8],  acc1[9],  acc1[10], acc1[11]);
    *(float4*)(dst + 28) = make_float4(acc1[12], acc1[13], acc1[14], acc1[15]);
}

__device__ __forceinline__ int refl(int i, int n) {
    if (i < 0) i = -i;
    if (i >= n) i = 2 * n - 2 - i;
    return i;
}

// ---------------- sliding-window attention: one thread per (b,head,pixel) ----
// q,k already l2-normalized. ao layout: [b][p][h*16+d] (pixel-major for oproj).
__global__ __launch_bounds__(256) void k_attn(
    const float* __restrict__ qh, const float* __restrict__ kh,
    const float* __restrict__ vv, float* __restrict__ ao)
{
    int gid = blockIdx.x * blockDim.x + threadIdx.x;   // (b*4+h)*HW + p
    int p  = gid & (HW_ - 1);
    int bh = gid >> 14;
    int y = p >> 7, x = p & (W_ - 1);

    const float* qp = qh + ((size_t)bh * HW_ + p) * HD_;
    float4 q0 = *(const float4*)(qp + 0);
    float4 q1 = *(const float4*)(qp + 4);
    float4 q2 = *(const float4*)(qp + 8);
    float4 q3 = *(const float4*)(qp + 12);

    float logit[WS_ * WS_];
    int   nidx [WS_ * WS_];
#pragma unroll
    for (int i = 0; i < WS_; ++i) {
        int ry = refl(y + i - PAD_, H_);
#pragma unroll
        for (int j = 0; j < WS_; ++j) {
            int rx = refl(x + j - PAD_, W_);
            int np_ = ry * W_ + rx;
            nidx[i*WS_ + j] = np_;
            const float* kp = kh + ((size_t)bh * HW_ + np_) * HD_;
            float4 ka = *(const float4*)(kp + 0);
            float4 kb = *(const float4*)(kp + 4);
            float4 kc = *(const float4*)(kp + 8);
            float4 kd = *(const float4*)(kp + 12);
            float d = 0.f;
            d = fmaf(q0.x, ka.x, d); d = fmaf(q0.y, ka.y, d);
            d = fmaf(q0.z, ka.z, d); d = fmaf(q0.w, ka.w, d);
            d = fmaf(q1.x, kb.x, d); d = fmaf(q1.y, kb.y, d);
            d = fmaf(q1.z, kb.z, d); d = fmaf(q1.w, kb.w, d);
            d = fmaf(q2.x, kc.x, d); d = fmaf(q2.y, kc.y, d);
            d = fmaf(q2.z, kc.z, d); d = fmaf(q2.w, kc.w, d);
            d = fmaf(q3.x, kd.x, d); d = fmaf(q3.y, kd.y, d);
            d = fmaf(q3.z, kd.z, d); d = fmaf(q3.w, kd.w, d);
            logit[i*WS_ + j] = d;
        }
    }

    float m = logit[0];
#pragma unroll
    for (int w = 1; w < WS_*WS_; ++w) m = fmaxf(m, logit[w]);
    float s = 0.f;
#pragma unroll
    for (int w = 0; w < WS_*WS_; ++w) { float e = expf(logit[w] - m); logit[w] = e; s += e; }
    float invs = 1.f / s;

    float a[HD_];
#pragma unroll
    for (int d = 0; d < HD_; ++d) a[d] = 0.f;
#pragma unroll
    for (int w = 0; w < WS_*WS_; ++w) {
        float wt = logit[w] * invs;
        const float* vp = vv + ((size_t)bh * HW_ + nidx[w]) * HD_;
        float4 va = *(const float4*)(vp + 0);
        float4 vb = *(const float4*)(vp + 4);
        float4 vc = *(const float4*)(vp + 8);
        float4 vd = *(const float4*)(vp + 12);
        a[0]  = fmaf(wt, va.x, a[0]);  a[1]  = fmaf(wt, va.y, a[1]);
        a[2]  = fmaf(wt, va.z, a[2]);  a[3]  = fmaf(wt, va.w, a[3]);
        a[4]  = fmaf(wt, vb.x, a[4]);  a[5]  = fmaf(wt, vb.y, a[5]);
        a[6]  = fmaf(wt, vb.z, a[6]);  a[7]  = fmaf(wt, vb.w, a[7]);
        a[8]  = fmaf(wt, vc.x, a[8]);  a[9]  = fmaf(wt, vc.y, a[9]);
        a[10] = fmaf(wt, vc.z, a[10]); a[11] = fmaf(wt, vc.w, a[11]);
        a[12] = fmaf(wt, vd.x, a[12]); a[13] = fmaf(wt, vd.y, a[13]);
        a[14] = fmaf(wt, vd.z, a[14]); a[15] = fmaf(wt, vd.w, a[15]);
    }

    int b = bh >> 2, h = bh & 3;
    float* aop = ao + ((size_t)b * HW_ + p) * AD_ + h * HD_;
    *(float4*)(aop + 0)  = make_float4(a[0],  a[1],  a[2],  a[3]);
    *(float4*)(aop + 4)  = make_float4(a[4],  a[5],  a[6],  a[7]);
    *(float4*)(aop + 8)  = make_float4(a[8],  a[9],  a[10], a[11]);
    *(float4*)(aop + 12) = make_float4(a[12], a[13], a[14], a[15]);
}

// ---------------- output projection: out[b, oc, p] = sum_c WoT[c][oc] * ao[b,p,c]
// Block = 4 waves over the same 64 pixels; each wave owns a 64-wide o-chunk.
__global__ __launch_bounds__(256) void k_oproj(
    const float* __restrict__ ao, const float* __restrict__ WoT,
    float* __restrict__ out)
{
    int lane = threadIdx.x & 63;
    int och  = __builtin_amdgcn_readfirstlane((int)(threadIdx.x >> 6)); // 0..3, SGPR
    int pix  = blockIdx.x * 64 + lane;                                  // 0..65535
    int b = pix >> 14;
    int p = pix & (HW_ - 1);
    const float* xp = ao + (size_t)pix * AD_;

    float acc[64];
#pragma unroll
    for (int o = 0; o < 64; ++o) acc[o] = 0.f;

    for (int c4 = 0; c4 < AD_ / 4; ++c4) {
        float4 xv = *(const float4*)(xp + c4 * 4);
#pragma unroll
        for (int cc = 0; cc < 4; ++cc) {
            float xs = (cc == 0) ? xv.x : (cc == 1) ? xv.y : (cc == 2) ? xv.z : xv.w;
            const float* wr = WoT + (size_t)(c4*4 + cc) * DIM_ + och * 64;  // uniform -> s_load
#pragma unroll
            for (int o = 0; o < 64; ++o) acc[o] = fmaf(wr[o], xs, acc[o]);
        }
    }

    float* op = out + (size_t)b * DIM_ * HW_ + (size_t)och * 64 * HW_ + p;
#pragma unroll
    for (int o = 0; o < 64; ++o) op[(size_t)o * HW_] = acc[o];
}

extern "C" void kernel_launch(void* const* d_in, const int* in_sizes, int n_in,
                              void* d_out, int out_size, void* d_ws, size_t ws_size,
                              hipStream_t stream) {
    const float* q_in  = (const float*)d_in[0];
    const float* kv_in = (const float*)d_in[1];
    const float* Wq    = (const float*)d_in[2];
    const float* Wk    = (const float*)d_in[3];
    const float* Wv    = (const float*)d_in[4];
    const float* Wo    = (const float*)d_in[5];
    float* out = (float*)d_out;

    float* wsf = (float*)d_ws;
    float* WqT = wsf;
    float* WkT = WqT + AD_ * DIM_;
    float* WvT = WkT + AD_ * DIM_;
    float* WoT = WvT + AD_ * DIM_;
    size_t tens = (size_t)B_ * HEADS_ * HW_ * HD_;   // 4,194,304 floats
    float* qh = WoT + AD_ * DIM_;
    float* kh = qh + tens;
    float* vv = kh + tens;
    float* ao = vv + tens;

    k_transpose_w<<<dim3(64), dim3(256), 0, stream>>>(Wq, Wk, Wv, Wo, WqT, WkT, WvT, WoT);
    k_qkv<<<dim3(HW_ * B_ / 128), dim3(768), 0, stream>>>(q_in, kv_in, WqT, WkT, WvT, qh, kh, vv);
    k_attn <<<dim3(1024), dim3(256), 0, stream>>>(qh, kh, vv, ao);
    k_oproj<<<dim3(1024), dim3(256), 0, stream>>>(ao, WoT, out);
}